// Round 2
// 704.220 us; speedup vs baseline: 1.7023x; 1.7023x over previous
//
#include <hip/hip_runtime.h>
#include <hip/hip_bf16.h>
#include <math.h>

// Problem constants (B=1, S=2048, D=1024, E=8, K=2, FF=4096)
#define T_      2048
#define D_      1024
#define E_      8
#define FF_     4096

typedef __attribute__((ext_vector_type(8))) short  bf16x8;   // MFMA A/B frag
typedef __attribute__((ext_vector_type(4))) float  f32x4;    // MFMA C/D frag
typedef __attribute__((ext_vector_type(4))) __bf16 b16x4;

// async global->LDS 16B copy. LDS dest is WAVE-UNIFORM base; HW adds lane*16.
static __device__ inline void async_copy16(const void* g, void* l) {
    __builtin_amdgcn_global_load_lds(
        (const __attribute__((address_space(1))) unsigned int*)g,
        (__attribute__((address_space(3))) unsigned int*)l, 16, 0, 0);
}

// ---------------------------------------------------------------------------
// fp32 -> bf16 bulk conversion (layout-preserving), grid-stride.
// ---------------------------------------------------------------------------
__global__ __launch_bounds__(256) void cvt_kernel(
    const float4* __restrict__ src, b16x4* __restrict__ dst, int n4)
{
    int i = blockIdx.x * 256 + threadIdx.x;
    int stride = gridDim.x * 256;
    for (; i < n4; i += stride) {
        float4 v = src[i];
        f32x4 vv; vv[0] = v.x; vv[1] = v.y; vv[2] = v.z; vv[3] = v.w;
        dst[i] = __builtin_convertvector(vv, b16x4);
    }
}

// ---------------------------------------------------------------------------
// Router (fp32): logits, top-2 + renorm, per-expert (token, weight) lists.
// Also converts h -> bf16 (hbf). Softmax denom cancels in top-2 renorm.
// ---------------------------------------------------------------------------
__global__ __launch_bounds__(256) void router_kernel(
    const float* __restrict__ h, const float* __restrict__ gw,
    __bf16* __restrict__ hbf, float* __restrict__ logits,
    int* __restrict__ counts, int* __restrict__ lists, float* __restrict__ wlist)
{
    int t = blockIdx.x * 4 + (threadIdx.x >> 6);
    int lane = threadIdx.x & 63;
    const float4* hrow = (const float4*)(h + (size_t)t * D_);   // 256 float4
    const float4* gw4  = (const float4*)gw;                     // [E][256]
    float part[E_];
#pragma unroll
    for (int e = 0; e < E_; ++e) part[e] = 0.f;
#pragma unroll 4
    for (int i = lane; i < 256; i += 64) {
        float4 v = hrow[i];
        f32x4 vv; vv[0] = v.x; vv[1] = v.y; vv[2] = v.z; vv[3] = v.w;
        b16x4 bv = __builtin_convertvector(vv, b16x4);
        *(b16x4*)(hbf + (size_t)t * D_ + i * 4) = bv;
#pragma unroll
        for (int e = 0; e < E_; ++e) {
            float4 g = gw4[e * 256 + i];
            part[e] += v.x * g.x + v.y * g.y + v.z * g.z + v.w * g.w;
        }
    }
#pragma unroll
    for (int e = 0; e < E_; ++e) {
        float v = part[e];
#pragma unroll
        for (int off = 32; off > 0; off >>= 1) v += __shfl_down(v, off, 64);
        part[e] = v;
    }
    if (lane == 0) {
        float* lo = logits + (size_t)t * E_;
#pragma unroll
        for (int e = 0; e < E_; ++e) lo[e] = part[e];
        int i0 = 0;
#pragma unroll
        for (int e = 1; e < E_; ++e) if (part[e] > part[i0]) i0 = e;
        int i1 = (i0 == 0) ? 1 : 0;
#pragma unroll
        for (int e = 0; e < E_; ++e)
            if (e != i0 && part[e] > part[i1]) i1 = e;
        float w1v = expf(part[i1] - part[i0]);
        float s = 1.0f + w1v;
        int p0 = atomicAdd(&counts[i0], 1);
        lists[i0 * T_ + p0] = t; wlist[i0 * T_ + p0] = 1.0f / s;
        int p1 = atomicAdd(&counts[i1], 1);
        lists[i1 * T_ + p1] = t; wlist[i1 * T_ + p1] = w1v / s;
    }
}

// Exclusive prefix of counts -> offs (8 values; trivial)
__global__ void prefix_kernel(const int* __restrict__ counts, int* __restrict__ offs) {
    if (threadIdx.x == 0) {
        int s = 0;
#pragma unroll
        for (int e = 0; e < E_; ++e) { offs[e] = s; s += counts[e]; }
    }
}

// ---------------------------------------------------------------------------
// K1: inter[row][ff] = silu(h@w1^T) * (h@w3^T), bf16, compact rows.
// 2-phase LDS double-buffered pipeline (T3 minimal recipe):
//   BM=64 tokens, BN=256 ff, BK=32. 8 waves, wave w owns 64tok x 32ff (both
//   mats): 16 MFMA : 8 ds_read_b128 per step. Staging via global_load_lds
//   (16B, wave-uniform LDS base), 36 x 1KB segments/step, 4-5 per wave.
// LDS chunk XOR-swizzle (c ^= row&3) applied on the GLOBAL source (m173) and
// on the ds_read offset -> 4-way worst-case instead of 8-16-way conflicts.
// MFMA 16x16x32 bf16: A lane=A[m=ln][k=q*8+j]; B lane=B[k=q*8+j][n=ln];
// C/D col=ln, row=q*4+reg.
// grid = mt(32) * 128slices, slice = e*16+nt  (same slice -> same XCD).
// ---------------------------------------------------------------------------
#define G1_SEGS 36
__global__ __launch_bounds__(512, 4) void gemm1_kernel(
    const __bf16* __restrict__ hbf,
    const __bf16* __restrict__ w1b, const __bf16* __restrict__ w3b,
    const int* __restrict__ counts, const int* __restrict__ offs,
    const int* __restrict__ lists, __bf16* __restrict__ inter)
{
    int bid   = blockIdx.x;
    int slice = bid & 127;        // e*16 + nt
    int tile  = bid >> 7;         // 0..31
    int nt    = slice & 15;       // ff tile of 256
    int e     = slice >> 4;
    int ne    = counts[e];
    if (tile * 64 >= ne) return;
    int gb = offs[e];

    __shared__ __bf16 sh[2][G1_SEGS * 512];   // 72 KB (2 x 36KB)

    int tid = threadIdx.x, lane = tid & 63, w = tid >> 6;
    int ln = lane & 15, q = lane >> 4;
    int r4 = lane >> 2, c4 = lane & 3;

    // ---- staging segment setup (global base ptrs at k=0, pre-swizzled) ----
    const __bf16* gs[5];
    int sseg[5];
#pragma unroll
    for (int i = 0; i < 5; ++i) {
        int s = w + i * 8;
        sseg[i] = s;
        gs[i] = hbf;   // dummy init
        if (s < 4) {                       // A: 64 token rows (16 per seg)
            int row = s * 16 + r4;
            int idx = tile * 64 + row; if (idx >= ne) idx = ne - 1;
            int tok = lists[e * T_ + idx];
            gs[i] = hbf + (size_t)tok * D_ + ((c4 ^ (row & 3)) * 8);
        } else if (s < 20) {               // B1: 256 ff rows
            int row = (s - 4) * 16 + r4;
            gs[i] = w1b + ((size_t)e * FF_ + nt * 256 + row) * D_
                        + ((c4 ^ (row & 3)) * 8);
        } else if (s < G1_SEGS) {          // B3: 256 ff rows
            int row = (s - 20) * 16 + r4;
            gs[i] = w3b + ((size_t)e * FF_ + nt * 256 + row) * D_
                        + ((c4 ^ (row & 3)) * 8);
        }
    }

    // step-invariant ds_read element offsets (within one buffer)
    int cxs = (q ^ (ln & 3)) * 8;          // swizzled k-chunk
    int aoff[4], boff[2];
#pragma unroll
    for (int mt = 0; mt < 4; ++mt) aoff[mt] = (mt * 16 + ln) * 32 + cxs;
#pragma unroll
    for (int nf = 0; nf < 2; ++nf)
        boff[nf] = 2048 + (w * 32 + nf * 16 + ln) * 32 + cxs;

    f32x4 up[4][2], gt[4][2];
#pragma unroll
    for (int mt = 0; mt < 4; ++mt)
#pragma unroll
        for (int nf = 0; nf < 2; ++nf) {
            up[mt][nf] = (f32x4){0.f, 0.f, 0.f, 0.f};
            gt[mt][nf] = (f32x4){0.f, 0.f, 0.f, 0.f};
        }

    // ---- prologue ----
#pragma unroll
    for (int i = 0; i < 5; ++i)
        if (sseg[i] < G1_SEGS)
            async_copy16(gs[i], &sh[0][sseg[i] * 512]);
    __syncthreads();

    // ---- 2-phase K loop: 32 steps of BK=32 ----
    for (int t = 0; t < 32; ++t) {
        if (t + 1 < 32) {
#pragma unroll
            for (int i = 0; i < 5; ++i)
                if (sseg[i] < G1_SEGS)
                    async_copy16(gs[i] + (t + 1) * 32,
                                 &sh[(t + 1) & 1][sseg[i] * 512]);
        }
        const __bf16* S = sh[t & 1];
        bf16x8 b1[2], b3[2];
#pragma unroll
        for (int nf = 0; nf < 2; ++nf) {
            b1[nf] = *(const bf16x8*)(S + boff[nf]);
            b3[nf] = *(const bf16x8*)(S + boff[nf] + 8192);
        }
#pragma unroll
        for (int mt = 0; mt < 4; ++mt) {
            bf16x8 a = *(const bf16x8*)(S + aoff[mt]);
#pragma unroll
            for (int nf = 0; nf < 2; ++nf) {
                up[mt][nf] = __builtin_amdgcn_mfma_f32_16x16x32_bf16(a, b1[nf], up[mt][nf], 0, 0, 0);
                gt[mt][nf] = __builtin_amdgcn_mfma_f32_16x16x32_bf16(a, b3[nf], gt[mt][nf], 0, 0, 0);
            }
        }
        __syncthreads();   // drains vmcnt (stage t+1 landed) + lgkm
    }

    // ---- epilogue: silu*gate, per-wave 16x16 transpose via LDS, b16x4 store
    __bf16* trw = (__bf16*)&sh[0][0] + w * 384;    // 16 x 24 elems per wave
    int ffb = nt * 256 + w * 32;
#pragma unroll
    for (int mt = 0; mt < 4; ++mt) {
        int idx = tile * 64 + mt * 16 + ln;
#pragma unroll
        for (int nf = 0; nf < 2; ++nf) {
#pragma unroll
            for (int r = 0; r < 4; ++r) {
                float u = up[mt][nf][r], g = gt[mt][nf][r];
                float val = (u / (1.f + expf(-u))) * g;     // silu(u)*g
                trw[(q * 4 + r) * 24 + ln] = (__bf16)val;   // row=token col=ff
            }
            __asm__ volatile("s_waitcnt lgkmcnt(0)" ::: "memory");
            b16x4 v4 = *(b16x4*)&trw[ln * 24 + q * 4];
            if (idx < ne)
                *(b16x4*)(inter + (size_t)(gb + idx) * FF_ + ffb + nf * 16 + q * 4) = v4;
            __asm__ volatile("s_waitcnt lgkmcnt(0)" ::: "memory");
        }
    }
}

// ---------------------------------------------------------------------------
// K2: out[t][d] += cw * (inter[row] . w2[e][d]), same 2-phase pipeline.
//   BM=128 tokens, BN=256 d, BK=32, K-split x4 (1024 each) for occupancy.
//   8 waves as 2x4, wave owns 64tok x 64d: 16 MFMA : 8 ds_read per step.
//   24 x 1KB staging segments/step (exactly 3 per wave).
// grid = mt(16) * 128slices, slice = e*16 + nd*4 + ks (same slice->same XCD).
// ---------------------------------------------------------------------------
#define G2_SEGS 24
__global__ __launch_bounds__(512, 4) void gemm2_kernel(
    const __bf16* __restrict__ inter, const __bf16* __restrict__ w2b,
    const int* __restrict__ counts, const int* __restrict__ offs,
    const int* __restrict__ lists, const float* __restrict__ wlist,
    float* __restrict__ out)
{
    int bid   = blockIdx.x;
    int slice = bid & 127;        // e*16 + nd*4 + ks
    int tile  = bid >> 7;         // 0..15
    int ks    = slice & 3;
    int nd    = (slice >> 2) & 3;
    int e     = slice >> 4;
    int ne    = counts[e];
    if (tile * 128 >= ne) return;
    int gb = offs[e];

    __shared__ __bf16 sh[2][G2_SEGS * 512];   // 48 KB
    __shared__ int    stok[128];
    __shared__ float  swgt[128];

    int tid = threadIdx.x, lane = tid & 63, w = tid >> 6;
    int ln = lane & 15, q = lane >> 4;
    int r4 = lane >> 2, c4 = lane & 3;
    int wm = w >> 2, wn = w & 3;

    // ---- staging segment setup ----
    const __bf16* gs[3];
#pragma unroll
    for (int i = 0; i < 3; ++i) {
        int s = w + i * 8;
        if (s < 8) {                        // A: 128 inter rows (compact)
            int row = s * 16 + r4;
            int idx = tile * 128 + row; if (idx >= ne) idx = ne - 1;
            gs[i] = inter + (size_t)(gb + idx) * FF_ + ks * 1024
                          + ((c4 ^ (row & 3)) * 8);
        } else {                            // B: 256 d rows of w2
            int row = (s - 8) * 16 + r4;
            gs[i] = w2b + ((size_t)e * D_ + nd * 256 + row) * FF_ + ks * 1024
                        + ((c4 ^ (row & 3)) * 8);
        }
    }

    int cxs = (q ^ (ln & 3)) * 8;
    int aoff[4], boff[4];
#pragma unroll
    for (int mt = 0; mt < 4; ++mt) aoff[mt] = (wm * 64 + mt * 16 + ln) * 32 + cxs;
#pragma unroll
    for (int nf = 0; nf < 4; ++nf)
        boff[nf] = 4096 + (wn * 64 + nf * 16 + ln) * 32 + cxs;

    f32x4 acc[4][4];
#pragma unroll
    for (int mt = 0; mt < 4; ++mt)
#pragma unroll
        for (int nf = 0; nf < 4; ++nf) acc[mt][nf] = (f32x4){0.f, 0.f, 0.f, 0.f};

    // ---- prologue: stage step 0, load token/weight table ----
#pragma unroll
    for (int i = 0; i < 3; ++i) {
        int s = w + i * 8;
        async_copy16(gs[i], &sh[0][s * 512]);
    }
    if (tid < 128) {
        int idx = tile * 128 + tid;
        int c   = idx < ne ? idx : ne - 1;
        stok[tid] = lists[e * T_ + c];
        swgt[tid] = (idx < ne) ? wlist[e * T_ + idx] : 0.f;
    }
    __syncthreads();

    // ---- 2-phase K loop: 32 steps of BK=32 (this K-split's 1024) ----
    for (int t = 0; t < 32; ++t) {
        if (t + 1 < 32) {
#pragma unroll
            for (int i = 0; i < 3; ++i) {
                int s = w + i * 8;
                async_copy16(gs[i] + (t + 1) * 32, &sh[(t + 1) & 1][s * 512]);
            }
        }
        const __bf16* S = sh[t & 1];
        bf16x8 b[4];
#pragma unroll
        for (int nf = 0; nf < 4; ++nf) b[nf] = *(const bf16x8*)(S + boff[nf]);
#pragma unroll
        for (int mt = 0; mt < 4; ++mt) {
            bf16x8 a = *(const bf16x8*)(S + aoff[mt]);
#pragma unroll
            for (int nf = 0; nf < 4; ++nf)
                acc[mt][nf] = __builtin_amdgcn_mfma_f32_16x16x32_bf16(a, b[nf], acc[mt][nf], 0, 0, 0);
        }
        __syncthreads();
    }

    // ---- epilogue: weighted atomic scatter. C/D: row=q*4+r (token), col=ln
    int dbase = nd * 256 + wn * 64;
#pragma unroll
    for (int mt = 0; mt < 4; ++mt) {
#pragma unroll
        for (int r = 0; r < 4; ++r) {
            int m = wm * 64 + mt * 16 + q * 4 + r;
            float wgt = swgt[m];
            if (wgt != 0.f) {
                int tok = stok[m];
#pragma unroll
                for (int nf = 0; nf < 4; ++nf)
                    atomicAdd(out + (size_t)tok * D_ + dbase + nf * 16 + ln,
                              wgt * acc[mt][nf][r]);
            }
        }
    }
}

extern "C" void kernel_launch(void* const* d_in, const int* in_sizes, int n_in,
                              void* d_out, int out_size, void* d_ws, size_t ws_size,
                              hipStream_t stream)
{
    const float* h  = (const float*)d_in[0];   // [1,2048,1024]
    const float* gw = (const float*)d_in[1];   // [8,1024]
    const float* w1 = (const float*)d_in[2];   // [8,4096,1024]
    const float* w3 = (const float*)d_in[3];   // [8,4096,1024]
    const float* w2 = (const float*)d_in[4];   // [8,1024,4096]

    float* out    = (float*)d_out;             // [2048*1024] then logits
    float* logits = out + (size_t)T_ * D_;     // [2048*8]

    // workspace layout
    const size_t W_ELEMS = (size_t)E_ * FF_ * D_;            // 33.55 M per tensor
    char*   ws     = (char*)d_ws;
    size_t  off    = 0;
    int*    counts = (int*)(ws + off); off += 128;
    int*    offs   = (int*)(ws + off); off += 128;
    int*    lists  = (int*)(ws + off); off += (size_t)E_ * T_ * 4;
    float*  wlist  = (float*)(ws + off); off += (size_t)E_ * T_ * 4;
    __bf16* hbf    = (__bf16*)(ws + off); off += (size_t)T_ * D_ * 2;      // 4 MB
    __bf16* inter  = (__bf16*)(ws + off); off += (size_t)T_ * 2 * FF_ * 2; // 32 MB
    __bf16* w1b    = (__bf16*)(ws + off); off += W_ELEMS * 2;  // 67 MB
    __bf16* w3b    = (__bf16*)(ws + off); off += W_ELEMS * 2;  // 67 MB
    __bf16* w2b    = (__bf16*)(ws + off); off += W_ELEMS * 2;  // 67 MB
    (void)ws_size;

    hipMemsetAsync(counts, 0, 256, stream);
    hipMemsetAsync(out, 0, (size_t)T_ * D_ * sizeof(float), stream);

    router_kernel<<<T_ / 4, 256, 0, stream>>>(h, gw, hbf, logits, counts, lists, wlist);
    prefix_kernel<<<1, 64, 0, stream>>>(counts, offs);

    int n4 = (int)(W_ELEMS / 4);
    cvt_kernel<<<4096, 256, 0, stream>>>((const float4*)w1, (b16x4*)w1b, n4);
    cvt_kernel<<<4096, 256, 0, stream>>>((const float4*)w3, (b16x4*)w3b, n4);
    cvt_kernel<<<4096, 256, 0, stream>>>((const float4*)w2, (b16x4*)w2b, n4);

    gemm1_kernel<<<32 * 128, 512, 0, stream>>>(hbf, w1b, w3b, counts, offs, lists, inter);
    gemm2_kernel<<<16 * 128, 512, 0, stream>>>(inter, w2b, counts, offs, lists, wlist, out);
}

// Round 3
// 664.342 us; speedup vs baseline: 1.8045x; 1.0600x over previous
//
#include <hip/hip_runtime.h>
#include <hip/hip_bf16.h>
#include <math.h>

// Problem constants (B=1, S=2048, D=1024, E=8, K=2, FF=4096)
#define T_      2048
#define D_      1024
#define E_      8
#define FF_     4096

typedef __attribute__((ext_vector_type(8))) short  bf16x8;   // MFMA A/B frag
typedef __attribute__((ext_vector_type(4))) float  f32x4;    // MFMA C/D frag
typedef __attribute__((ext_vector_type(4))) __bf16 b16x4;

// async global->LDS 16B copy. LDS dest is WAVE-UNIFORM base; HW adds lane*16.
static __device__ inline void async_copy16(const void* g, void* l) {
    __builtin_amdgcn_global_load_lds(
        (const __attribute__((address_space(1))) unsigned int*)g,
        (__attribute__((address_space(3))) unsigned int*)l, 16, 0, 0);
}

// ---------------------------------------------------------------------------
// fp32 -> bf16 bulk conversion (layout-preserving), grid-stride.
// ---------------------------------------------------------------------------
__global__ __launch_bounds__(256) void cvt_kernel(
    const float4* __restrict__ src, b16x4* __restrict__ dst, int n4)
{
    int i = blockIdx.x * 256 + threadIdx.x;
    int stride = gridDim.x * 256;
    for (; i < n4; i += stride) {
        float4 v = src[i];
        f32x4 vv; vv[0] = v.x; vv[1] = v.y; vv[2] = v.z; vv[3] = v.w;
        dst[i] = __builtin_convertvector(vv, b16x4);
    }
}

// ---------------------------------------------------------------------------
// Router (fp32): logits, top-2 + renorm, per-expert (token, weight) lists.
// Also converts h -> bf16 (hbf). Softmax denom cancels in top-2 renorm.
// ---------------------------------------------------------------------------
__global__ __launch_bounds__(256) void router_kernel(
    const float* __restrict__ h, const float* __restrict__ gw,
    __bf16* __restrict__ hbf, float* __restrict__ logits,
    int* __restrict__ counts, int* __restrict__ lists, float* __restrict__ wlist)
{
    int t = blockIdx.x * 4 + (threadIdx.x >> 6);
    int lane = threadIdx.x & 63;
    const float4* hrow = (const float4*)(h + (size_t)t * D_);   // 256 float4
    const float4* gw4  = (const float4*)gw;                     // [E][256]
    float part[E_];
#pragma unroll
    for (int e = 0; e < E_; ++e) part[e] = 0.f;
#pragma unroll 4
    for (int i = lane; i < 256; i += 64) {
        float4 v = hrow[i];
        f32x4 vv; vv[0] = v.x; vv[1] = v.y; vv[2] = v.z; vv[3] = v.w;
        b16x4 bv = __builtin_convertvector(vv, b16x4);
        *(b16x4*)(hbf + (size_t)t * D_ + i * 4) = bv;
#pragma unroll
        for (int e = 0; e < E_; ++e) {
            float4 g = gw4[e * 256 + i];
            part[e] += v.x * g.x + v.y * g.y + v.z * g.z + v.w * g.w;
        }
    }
#pragma unroll
    for (int e = 0; e < E_; ++e) {
        float v = part[e];
#pragma unroll
        for (int off = 32; off > 0; off >>= 1) v += __shfl_down(v, off, 64);
        part[e] = v;
    }
    if (lane == 0) {
        float* lo = logits + (size_t)t * E_;
#pragma unroll
        for (int e = 0; e < E_; ++e) lo[e] = part[e];
        int i0 = 0;
#pragma unroll
        for (int e = 1; e < E_; ++e) if (part[e] > part[i0]) i0 = e;
        int i1 = (i0 == 0) ? 1 : 0;
#pragma unroll
        for (int e = 0; e < E_; ++e)
            if (e != i0 && part[e] > part[i1]) i1 = e;
        float w1v = expf(part[i1] - part[i0]);
        float s = 1.0f + w1v;
        int p0 = atomicAdd(&counts[i0], 1);
        lists[i0 * T_ + p0] = t; wlist[i0 * T_ + p0] = 1.0f / s;
        int p1 = atomicAdd(&counts[i1], 1);
        lists[i1 * T_ + p1] = t; wlist[i1 * T_ + p1] = w1v / s;
    }
}

// Exclusive prefix of counts -> offs (8 values; trivial)
__global__ void prefix_kernel(const int* __restrict__ counts, int* __restrict__ offs) {
    if (threadIdx.x == 0) {
        int s = 0;
#pragma unroll
        for (int e = 0; e < E_; ++e) { offs[e] = s; s += counts[e]; }
    }
}

// ---------------------------------------------------------------------------
// K1: inter[row][ff] = silu(h@w1^T) * (h@w3^T), bf16, compact rows.
// 2-phase LDS double-buffered pipeline. BM=64, BN=256, BK=32; 8 waves,
// wave w owns 64tok x 32ff of BOTH mats: 16 MFMA : 8 ds_read_b128 per step.
// Dispatch reorder: bid = sg*256 + tile*8 + sx  (sx = XCD). Same-slice tiles
// are dispatch-adjacent AND XCD-pinned -> concurrent weight working set per
// XCD ~2 slices x 1MB < 4MB L2 -> each weight byte fetched ~once from HBM.
// LDS swizzle: chunk ^= (row>>1)&3 on global SOURCE (gload_lds writes linear,
// m173) and on ds_read -> 2-way max bank aliasing (free, m136).
// MFMA 16x16x32 bf16: A lane=A[m=ln][k=q*8+j]; B lane=B[k=q*8+j][n=ln];
// C/D col=ln, row=q*4+reg.
// ---------------------------------------------------------------------------
#define G1_SEGS 36
__global__ __launch_bounds__(512, 4) void gemm1_kernel(
    const __bf16* __restrict__ hbf,
    const __bf16* __restrict__ w1b, const __bf16* __restrict__ w3b,
    const int* __restrict__ counts, const int* __restrict__ offs,
    const int* __restrict__ lists, __bf16* __restrict__ inter)
{
    int bid   = blockIdx.x;
    int sx    = bid & 7;          // XCD id (bid % 8)
    int rr    = bid >> 3;
    int tile  = rr & 31;          // 0..31  (adjacent bids -> adjacent tiles)
    int sg    = rr >> 5;          // 0..15
    int slice = sg * 8 + sx;      // 0..127
    int nt    = slice & 15;       // ff tile of 256
    int e     = slice >> 4;
    int ne    = counts[e];
    if (tile * 64 >= ne) return;
    int gb = offs[e];

    __shared__ __bf16 sh[2][G1_SEGS * 512];   // 72 KB (2 x 36KB)

    int tid = threadIdx.x, lane = tid & 63, w = tid >> 6;
    int ln = lane & 15, q = lane >> 4;
    int r4 = lane >> 2, c4 = lane & 3;

    // ---- staging segment setup (global base ptrs at k=0, pre-swizzled) ----
    const __bf16* gs[5];
    int sseg[5];
#pragma unroll
    for (int i = 0; i < 5; ++i) {
        int s = w + i * 8;
        sseg[i] = s;
        gs[i] = hbf;   // dummy init
        if (s < 4) {                       // A: 64 token rows (16 per seg)
            int row = s * 16 + r4;
            int idx = tile * 64 + row; if (idx >= ne) idx = ne - 1;
            int tok = lists[e * T_ + idx];
            gs[i] = hbf + (size_t)tok * D_ + ((c4 ^ ((row >> 1) & 3)) * 8);
        } else if (s < 20) {               // B1: 256 ff rows
            int row = (s - 4) * 16 + r4;
            gs[i] = w1b + ((size_t)e * FF_ + nt * 256 + row) * D_
                        + ((c4 ^ ((row >> 1) & 3)) * 8);
        } else if (s < G1_SEGS) {          // B3: 256 ff rows
            int row = (s - 20) * 16 + r4;
            gs[i] = w3b + ((size_t)e * FF_ + nt * 256 + row) * D_
                        + ((c4 ^ ((row >> 1) & 3)) * 8);
        }
    }

    // step-invariant ds_read element offsets (within one buffer)
    int cxs = (q ^ ((ln >> 1) & 3)) * 8;   // swizzled k-chunk
    int aoff[4], boff[2];
#pragma unroll
    for (int mt = 0; mt < 4; ++mt) aoff[mt] = (mt * 16 + ln) * 32 + cxs;
#pragma unroll
    for (int nf = 0; nf < 2; ++nf)
        boff[nf] = 2048 + (w * 32 + nf * 16 + ln) * 32 + cxs;

    f32x4 up[4][2], gt[4][2];
#pragma unroll
    for (int mt = 0; mt < 4; ++mt)
#pragma unroll
        for (int nf = 0; nf < 2; ++nf) {
            up[mt][nf] = (f32x4){0.f, 0.f, 0.f, 0.f};
            gt[mt][nf] = (f32x4){0.f, 0.f, 0.f, 0.f};
        }

    // ---- prologue ----
#pragma unroll
    for (int i = 0; i < 5; ++i)
        if (sseg[i] < G1_SEGS)
            async_copy16(gs[i], &sh[0][sseg[i] * 512]);
    __syncthreads();

    // ---- 2-phase K loop: 32 steps of BK=32 ----
    for (int t = 0; t < 32; ++t) {
        if (t + 1 < 32) {
#pragma unroll
            for (int i = 0; i < 5; ++i)
                if (sseg[i] < G1_SEGS)
                    async_copy16(gs[i] + (t + 1) * 32,
                                 &sh[(t + 1) & 1][sseg[i] * 512]);
        }
        const __bf16* S = sh[t & 1];
        bf16x8 b1[2], b3[2];
#pragma unroll
        for (int nf = 0; nf < 2; ++nf) {
            b1[nf] = *(const bf16x8*)(S + boff[nf]);
            b3[nf] = *(const bf16x8*)(S + boff[nf] + 8192);
        }
#pragma unroll
        for (int mt = 0; mt < 4; ++mt) {
            bf16x8 a = *(const bf16x8*)(S + aoff[mt]);
#pragma unroll
            for (int nf = 0; nf < 2; ++nf) {
                up[mt][nf] = __builtin_amdgcn_mfma_f32_16x16x32_bf16(a, b1[nf], up[mt][nf], 0, 0, 0);
                gt[mt][nf] = __builtin_amdgcn_mfma_f32_16x16x32_bf16(a, b3[nf], gt[mt][nf], 0, 0, 0);
            }
        }
        __syncthreads();   // drains vmcnt (stage t+1 landed) + lgkm
    }

    // ---- epilogue: silu*gate, per-wave 16x16 transpose via LDS, b16x4 store
    __bf16* trw = (__bf16*)&sh[0][0] + w * 384;    // 16 x 24 elems per wave
    int ffb = nt * 256 + w * 32;
#pragma unroll
    for (int mt = 0; mt < 4; ++mt) {
        int idx = tile * 64 + mt * 16 + ln;
#pragma unroll
        for (int nf = 0; nf < 2; ++nf) {
#pragma unroll
            for (int r = 0; r < 4; ++r) {
                float u = up[mt][nf][r], g = gt[mt][nf][r];
                float val = (u / (1.f + expf(-u))) * g;     // silu(u)*g
                trw[(q * 4 + r) * 24 + ln] = (__bf16)val;   // row=token col=ff
            }
            __asm__ volatile("s_waitcnt lgkmcnt(0)" ::: "memory");
            b16x4 v4 = *(b16x4*)&trw[ln * 24 + q * 4];
            if (idx < ne)
                *(b16x4*)(inter + (size_t)(gb + idx) * FF_ + ffb + nf * 16 + q * 4) = v4;
            __asm__ volatile("s_waitcnt lgkmcnt(0)" ::: "memory");
        }
    }
}

// ---------------------------------------------------------------------------
// K2: out[t][d] += cw * (inter[row] . w2[e][d]), same 2-phase pipeline.
//   BM=128 tokens, BN=256 d, BK=32, K-split x4 (1024 each) for occupancy.
//   8 waves as 2x4, wave owns 64tok x 64d: 16 MFMA : 8 ds_read per step.
// Same dispatch reorder (bid = sg*128 + tile*8 + sx) and 2-way swizzle.
// ---------------------------------------------------------------------------
#define G2_SEGS 24
__global__ __launch_bounds__(512, 4) void gemm2_kernel(
    const __bf16* __restrict__ inter, const __bf16* __restrict__ w2b,
    const int* __restrict__ counts, const int* __restrict__ offs,
    const int* __restrict__ lists, const float* __restrict__ wlist,
    float* __restrict__ out)
{
    int bid   = blockIdx.x;
    int sx    = bid & 7;          // XCD id
    int rr    = bid >> 3;
    int tile  = rr & 15;          // 0..15 (adjacent bids -> adjacent tiles)
    int sg    = rr >> 4;          // 0..15
    int slice = sg * 8 + sx;      // 0..127
    int ks    = slice & 3;
    int nd    = (slice >> 2) & 3;
    int e     = slice >> 4;
    int ne    = counts[e];
    if (tile * 128 >= ne) return;
    int gb = offs[e];

    __shared__ __bf16 sh[2][G2_SEGS * 512];   // 48 KB
    __shared__ int    stok[128];
    __shared__ float  swgt[128];

    int tid = threadIdx.x, lane = tid & 63, w = tid >> 6;
    int ln = lane & 15, q = lane >> 4;
    int r4 = lane >> 2, c4 = lane & 3;
    int wm = w >> 2, wn = w & 3;

    // ---- staging segment setup ----
    const __bf16* gs[3];
#pragma unroll
    for (int i = 0; i < 3; ++i) {
        int s = w + i * 8;
        if (s < 8) {                        // A: 128 inter rows (compact)
            int row = s * 16 + r4;
            int idx = tile * 128 + row; if (idx >= ne) idx = ne - 1;
            gs[i] = inter + (size_t)(gb + idx) * FF_ + ks * 1024
                          + ((c4 ^ ((row >> 1) & 3)) * 8);
        } else {                            // B: 256 d rows of w2
            int row = (s - 8) * 16 + r4;
            gs[i] = w2b + ((size_t)e * D_ + nd * 256 + row) * FF_ + ks * 1024
                        + ((c4 ^ ((row >> 1) & 3)) * 8);
        }
    }

    int cxs = (q ^ ((ln >> 1) & 3)) * 8;
    int aoff[4], boff[4];
#pragma unroll
    for (int mt = 0; mt < 4; ++mt) aoff[mt] = (wm * 64 + mt * 16 + ln) * 32 + cxs;
#pragma unroll
    for (int nf = 0; nf < 4; ++nf)
        boff[nf] = 4096 + (wn * 64 + nf * 16 + ln) * 32 + cxs;

    f32x4 acc[4][4];
#pragma unroll
    for (int mt = 0; mt < 4; ++mt)
#pragma unroll
        for (int nf = 0; nf < 4; ++nf) acc[mt][nf] = (f32x4){0.f, 0.f, 0.f, 0.f};

    // ---- prologue: stage step 0, load token/weight table ----
#pragma unroll
    for (int i = 0; i < 3; ++i) {
        int s = w + i * 8;
        async_copy16(gs[i], &sh[0][s * 512]);
    }
    if (tid < 128) {
        int idx = tile * 128 + tid;
        int c   = idx < ne ? idx : ne - 1;
        stok[tid] = lists[e * T_ + c];
        swgt[tid] = (idx < ne) ? wlist[e * T_ + idx] : 0.f;
    }
    __syncthreads();

    // ---- 2-phase K loop: 32 steps of BK=32 (this K-split's 1024) ----
    for (int t = 0; t < 32; ++t) {
        if (t + 1 < 32) {
#pragma unroll
            for (int i = 0; i < 3; ++i) {
                int s = w + i * 8;
                async_copy16(gs[i] + (t + 1) * 32, &sh[(t + 1) & 1][s * 512]);
            }
        }
        const __bf16* S = sh[t & 1];
        bf16x8 b[4];
#pragma unroll
        for (int nf = 0; nf < 4; ++nf) b[nf] = *(const bf16x8*)(S + boff[nf]);
#pragma unroll
        for (int mt = 0; mt < 4; ++mt) {
            bf16x8 a = *(const bf16x8*)(S + aoff[mt]);
#pragma unroll
            for (int nf = 0; nf < 4; ++nf)
                acc[mt][nf] = __builtin_amdgcn_mfma_f32_16x16x32_bf16(a, b[nf], acc[mt][nf], 0, 0, 0);
        }
        __syncthreads();
    }

    // ---- epilogue: weighted atomic scatter. C/D: row=q*4+r (token), col=ln
    int dbase = nd * 256 + wn * 64;
#pragma unroll
    for (int mt = 0; mt < 4; ++mt) {
#pragma unroll
        for (int r = 0; r < 4; ++r) {
            int m = wm * 64 + mt * 16 + q * 4 + r;
            float wgt = swgt[m];
            if (wgt != 0.f) {
                int tok = stok[m];
#pragma unroll
                for (int nf = 0; nf < 4; ++nf)
                    atomicAdd(out + (size_t)tok * D_ + dbase + nf * 16 + ln,
                              wgt * acc[mt][nf][r]);
            }
        }
    }
}

extern "C" void kernel_launch(void* const* d_in, const int* in_sizes, int n_in,
                              void* d_out, int out_size, void* d_ws, size_t ws_size,
                              hipStream_t stream)
{
    const float* h  = (const float*)d_in[0];   // [1,2048,1024]
    const float* gw = (const float*)d_in[1];   // [8,1024]
    const float* w1 = (const float*)d_in[2];   // [8,4096,1024]
    const float* w3 = (const float*)d_in[3];   // [8,4096,1024]
    const float* w2 = (const float*)d_in[4];   // [8,1024,4096]

    float* out    = (float*)d_out;             // [2048*1024] then logits
    float* logits = out + (size_t)T_ * D_;     // [2048*8]

    // workspace layout
    const size_t W_ELEMS = (size_t)E_ * FF_ * D_;            // 33.55 M per tensor
    char*   ws     = (char*)d_ws;
    size_t  off    = 0;
    int*    counts = (int*)(ws + off); off += 128;
    int*    offs   = (int*)(ws + off); off += 128;
    int*    lists  = (int*)(ws + off); off += (size_t)E_ * T_ * 4;
    float*  wlist  = (float*)(ws + off); off += (size_t)E_ * T_ * 4;
    __bf16* hbf    = (__bf16*)(ws + off); off += (size_t)T_ * D_ * 2;      // 4 MB
    __bf16* inter  = (__bf16*)(ws + off); off += (size_t)T_ * 2 * FF_ * 2; // 32 MB
    __bf16* w1b    = (__bf16*)(ws + off); off += W_ELEMS * 2;  // 67 MB
    __bf16* w3b    = (__bf16*)(ws + off); off += W_ELEMS * 2;  // 67 MB
    __bf16* w2b    = (__bf16*)(ws + off); off += W_ELEMS * 2;  // 67 MB
    (void)ws_size;

    hipMemsetAsync(counts, 0, 256, stream);
    hipMemsetAsync(out, 0, (size_t)T_ * D_ * sizeof(float), stream);

    router_kernel<<<T_ / 4, 256, 0, stream>>>(h, gw, hbf, logits, counts, lists, wlist);
    prefix_kernel<<<1, 64, 0, stream>>>(counts, offs);

    int n4 = (int)(W_ELEMS / 4);
    cvt_kernel<<<4096, 256, 0, stream>>>((const float4*)w1, (b16x4*)w1b, n4);
    cvt_kernel<<<4096, 256, 0, stream>>>((const float4*)w3, (b16x4*)w3b, n4);
    cvt_kernel<<<4096, 256, 0, stream>>>((const float4*)w2, (b16x4*)w2b, n4);

    gemm1_kernel<<<32 * 128, 512, 0, stream>>>(hbf, w1b, w3b, counts, offs, lists, inter);
    gemm2_kernel<<<16 * 128, 512, 0, stream>>>(inter, w2b, counts, offs, lists, wlist, out);
}